// Round 2
// baseline (534.235 us; speedup 1.0000x reference)
//
#include <hip/hip_runtime.h>
#include <hip/hip_bf16.h>
#include <stdint.h>

#define NTOT 65536   // B * N_NODE
#define NNODE 2048
#define CIN 12

__device__ __forceinline__ float bf2f(uint32_t u) {
    union { uint32_t i; float f; } v; v.i = u << 16; return v.f;
}
__device__ __forceinline__ uint16_t f2bf(float f) {
    union { float f; uint32_t i; } v; v.f = f;
    uint32_t x = v.i;
    uint32_t r = x + 0x7fffu + ((x >> 16) & 1u);
    return (uint16_t)(r >> 16);
}
__device__ __forceinline__ float sigmf(float x) { return 1.0f / (1.0f + __expf(-x)); }
__device__ __forceinline__ float lrelu(float v) { return v > 0.f ? v : 0.2f * v; }

// ---------------- dtype / layout detection ----------------
// flags[0]: 1 = float inputs are bf16, 0 = fp32
// flags[1]: edge_index element stride in 32-bit words (1 = int32, 2 = int64)
__global__ void k_detect(const uint16_t* __restrict__ x16, const int* __restrict__ e32,
                         int E, int* __restrict__ flags) {
    if (threadIdx.x == 0 && blockIdx.x == 0) {
        int sane = 0;
        for (int i = 0; i < 128; i++) {
            uint32_t u = x16[2 * i];
            uint32_t ex = (u >> 7) & 0xFF;
            if (ex >= 0x60 && ex <= 0x9F) sane++;   // |v| roughly in [2^-31, 2^32]
        }
        flags[0] = (sane >= 100) ? 1 : 0;
        int nz = 0;
        for (int i = 0; i < 64; i++)
            if (e32[2 * i + 1] != 0) nz++;
        flags[1] = (nz == 0) ? 2 : 1;
    }
}

// ---------------- input normalization to fp32 ----------------
__device__ __forceinline__ void cvt(const void* s, float* d, int i, int bf) {
    d[i] = bf ? bf2f(((const uint16_t*)s)[i]) : ((const float*)s)[i];
}

// ws float offsets of normalized inputs (all 16-float aligned)
#define O_X    16
#define O_WG   786448
#define O_AS   787600
#define O_AD   787696
#define O_BIAS 787792
#define O_WIH1 787808
#define O_WHH1 1049952
#define O_BIH1 1054048
#define O_BHH1 1054176
#define O_WIH2 1054304
#define O_WHH2 1070688
#define O_BIH2 1136224
#define O_BHH2 1136736
#define O_WLIN 1137248
#define O_BLIN 3496544
#define O_CONV_END 3514976

__global__ void __launch_bounds__(256) k_conv(
    const void* x, const void* wg, const void* as_, const void* ad_, const void* bs,
    const void* w1, const void* wh1, const void* b1, const void* bb1,
    const void* w2, const void* wh2, const void* b2, const void* bb2,
    const void* wl, const void* bl, float* __restrict__ ws, const int* __restrict__ flags) {
    int bf = flags[0];
    int i = blockIdx.x * 256 + threadIdx.x;
    if (i < 786432)  { cvt(x,   ws + O_X,    i, bf); return; } i -= 786432;
    if (i < 1152)    { cvt(wg,  ws + O_WG,   i, bf); return; } i -= 1152;
    if (i < 96)      { cvt(as_, ws + O_AS,   i, bf); return; } i -= 96;
    if (i < 96)      { cvt(ad_, ws + O_AD,   i, bf); return; } i -= 96;
    if (i < 12)      { cvt(bs,  ws + O_BIAS, i, bf); return; } i -= 12;
    if (i < 262144)  { cvt(w1,  ws + O_WIH1, i, bf); return; } i -= 262144;
    if (i < 4096)    { cvt(wh1, ws + O_WHH1, i, bf); return; } i -= 4096;
    if (i < 128)     { cvt(b1,  ws + O_BIH1, i, bf); return; } i -= 128;
    if (i < 128)     { cvt(bb1, ws + O_BHH1, i, bf); return; } i -= 128;
    if (i < 16384)   { cvt(w2,  ws + O_WIH2, i, bf); return; } i -= 16384;
    if (i < 65536)   { cvt(wh2, ws + O_WHH2, i, bf); return; } i -= 65536;
    if (i < 512)     { cvt(b2,  ws + O_BIH2, i, bf); return; } i -= 512;
    if (i < 512)     { cvt(bb2, ws + O_BHH2, i, bf); return; } i -= 512;
    if (i < 2359296) { cvt(wl,  ws + O_WLIN, i, bf); return; } i -= 2359296;
    if (i < 18432)   { cvt(bl,  ws + O_BLIN, i, bf); }
}

__global__ void k_zero(int* __restrict__ p) {
    p[blockIdx.x * 256 + threadIdx.x] = 0;
}

// ---------- GAT node transform: hf[n][96] = x[n][:] @ W_gat ----------
__global__ void k_node_feats(const float* __restrict__ x, const float* __restrict__ Wg,
                             float* __restrict__ hf) {
    int idx = blockIdx.x * 256 + threadIdx.x;   // NTOT*96
    int n = idx / 96, o = idx % 96;
    const float* xr = x + n * CIN;
    float acc = 0.f;
#pragma unroll
    for (int k = 0; k < CIN; k++) acc += xr[k] * Wg[k * 96 + o];
    hf[idx] = acc;
}

// ---------- attention scores ----------
__global__ void k_att(const float* __restrict__ hf, const float* __restrict__ att_s,
                      const float* __restrict__ att_d, float* __restrict__ a_s,
                      float* __restrict__ a_d) {
    int idx = blockIdx.x * 256 + threadIdx.x;   // NTOT*8
    int n = idx >> 3, h = idx & 7;
    const float* hr = hf + n * 96 + h * 12;
    float s = 0.f, d = 0.f;
#pragma unroll
    for (int c = 0; c < 12; c++) {
        float v = hr[c];
        s += v * att_s[h * 12 + c];
        d += v * att_d[h * 12 + c];
    }
    a_s[idx] = s; a_d[idx] = d;
}

// ---------- CSR build ----------
__global__ void k_hist(const int* __restrict__ e, int E, const int* __restrict__ flags,
                       int* __restrict__ deg) {
    int i = blockIdx.x * 256 + threadIdx.x;
    if (i < E) {
        long st = flags[1];
        atomicAdd(&deg[e[st * (E + i)]], 1);
    }
}

__global__ void k_scan1(const int* __restrict__ deg, int* __restrict__ bsum) {
    __shared__ int s[256];
    s[threadIdx.x] = deg[blockIdx.x * 256 + threadIdx.x];
    __syncthreads();
    for (int off = 128; off > 0; off >>= 1) {
        if (threadIdx.x < off) s[threadIdx.x] += s[threadIdx.x + off];
        __syncthreads();
    }
    if (threadIdx.x == 0) bsum[blockIdx.x] = s[0];
}

__global__ void k_scan2(const int* __restrict__ bsum, int* __restrict__ boff) {
    __shared__ int s[256];
    int t = threadIdx.x;
    int v = bsum[t];
    s[t] = v; __syncthreads();
    for (int off = 1; off < 256; off <<= 1) {
        int a = (t >= off) ? s[t - off] : 0;
        __syncthreads();
        s[t] += a;
        __syncthreads();
    }
    boff[t] = s[t] - v;
}

__global__ void k_scan3(const int* __restrict__ deg, const int* __restrict__ boff,
                        int* __restrict__ offs) {
    __shared__ int s[256];
    int t = threadIdx.x;
    int i = blockIdx.x * 256 + t;
    int v = deg[i];
    s[t] = v; __syncthreads();
    for (int off = 1; off < 256; off <<= 1) {
        int a = (t >= off) ? s[t - off] : 0;
        __syncthreads();
        s[t] += a;
        __syncthreads();
    }
    offs[i] = boff[blockIdx.x] + s[t] - v;
}

__global__ void k_scatter(const int* __restrict__ e, int E, const int* __restrict__ flags,
                          const int* __restrict__ offs, int* __restrict__ cur,
                          int* __restrict__ ssrc) {
    int i = blockIdx.x * 256 + threadIdx.x;
    if (i < E) {
        long st = flags[1];
        int s = e[st * i];
        int d = e[st * (E + i)];
        int pos = offs[d] + atomicAdd(&cur[d], 1);
        ssrc[pos] = s;
    }
}

// ---------- GAT aggregation: one wave per node ----------
__global__ void __launch_bounds__(256) k_agg(
    const float* __restrict__ hf, const float* __restrict__ a_s, const float* __restrict__ a_d,
    const int* __restrict__ offs, const int* __restrict__ deg, const int* __restrict__ ssrc,
    const float* __restrict__ bias, float* __restrict__ gT) {
    __shared__ float lm[4 * 8], ldn[4 * 8], lacc[4 * 96];
    int tid = threadIdx.x;
    int wave = tid >> 6, lane = tid & 63;
    int node = blockIdx.x * 4 + wave;
    int beg = offs[node];
    int d = deg[node];

    const float4* s4 = (const float4*)a_s;
    const float4* d4 = (const float4*)a_d;
    float4 dd0 = d4[node * 2], dd1 = d4[node * 2 + 1];
    float4 ss0 = s4[node * 2], ss1 = s4[node * 2 + 1];
    float ad[8] = {dd0.x, dd0.y, dd0.z, dd0.w, dd1.x, dd1.y, dd1.z, dd1.w};
    float asf[8] = {ss0.x, ss0.y, ss0.z, ss0.w, ss1.x, ss1.y, ss1.z, ss1.w};

    float m[8], sl[8];
#pragma unroll
    for (int h = 0; h < 8; h++) { sl[h] = lrelu(asf[h] + ad[h]); m[h] = sl[h]; }

    for (int k = lane; k < d; k += 64) {
        int s = ssrc[beg + k];
        float4 q0 = s4[s * 2], q1 = s4[s * 2 + 1];
        float q[8] = {q0.x, q0.y, q0.z, q0.w, q1.x, q1.y, q1.z, q1.w};
#pragma unroll
        for (int h = 0; h < 8; h++) {
            float v = lrelu(q[h] + ad[h]);
            if (v > m[h]) m[h] = v;
        }
    }
#pragma unroll
    for (int h = 0; h < 8; h++) {
#pragma unroll
        for (int off = 32; off > 0; off >>= 1) {
            float o = __shfl_xor(m[h], off, 64);
            if (o > m[h]) m[h] = o;
        }
    }

    float den[8];
#pragma unroll
    for (int h = 0; h < 8; h++) den[h] = (lane == 0) ? __expf(sl[h] - m[h]) : 0.f;
    for (int k = lane; k < d; k += 64) {
        int s = ssrc[beg + k];
        float4 q0 = s4[s * 2], q1 = s4[s * 2 + 1];
        float q[8] = {q0.x, q0.y, q0.z, q0.w, q1.x, q1.y, q1.z, q1.w};
#pragma unroll
        for (int h = 0; h < 8; h++) den[h] += __expf(lrelu(q[h] + ad[h]) - m[h]);
    }
#pragma unroll
    for (int h = 0; h < 8; h++) {
#pragma unroll
        for (int off = 32; off > 0; off >>= 1) den[h] += __shfl_xor(den[h], off, 64);
    }

    if (lane == 0) {
#pragma unroll
        for (int h = 0; h < 8; h++) { lm[wave * 8 + h] = m[h]; ldn[wave * 8 + h] = den[h]; }
    }
    __syncthreads();

    int ch0 = lane, head0 = lane / 12;
    int ch1 = lane + 64, head1 = (lane + 64) / 12;
    bool has1 = lane < 32;
    float m0 = lm[wave * 8 + head0];
    float di0 = 1.f / ldn[wave * 8 + head0];
    float ad0 = a_d[node * 8 + head0];
    float sl0 = lrelu(a_s[node * 8 + head0] + ad0);
    float acc0 = __expf(sl0 - m0) * hf[node * 96 + ch0];
    float m1 = 0.f, di1 = 0.f, ad1 = 0.f, acc1 = 0.f;
    if (has1) {
        m1 = lm[wave * 8 + head1];
        di1 = 1.f / ldn[wave * 8 + head1];
        ad1 = a_d[node * 8 + head1];
        float sl1 = lrelu(a_s[node * 8 + head1] + ad1);
        acc1 = __expf(sl1 - m1) * hf[node * 96 + ch1];
    }
    for (int e = beg; e < beg + d; ++e) {
        int s = ssrc[e];
        float v0 = lrelu(a_s[s * 8 + head0] + ad0);
        acc0 += __expf(v0 - m0) * hf[s * 96 + ch0];
        if (has1) {
            float v1 = lrelu(a_s[s * 8 + head1] + ad1);
            acc1 += __expf(v1 - m1) * hf[s * 96 + ch1];
        }
    }
    lacc[wave * 96 + ch0] = acc0 * di0;
    if (has1) lacc[wave * 96 + ch1] = acc1 * di1;
    __syncthreads();

    if (lane < 12) {
        float s = 0.f;
#pragma unroll
        for (int h = 0; h < 8; h++) s += lacc[wave * 96 + h * 12 + lane];
        gT[lane * NTOT + node] = s * 0.125f + bias[lane];
    }
}

// ---------- Z1[t,b,row] = seq[t,b,:] @ Wih1[row,:] + biases ----------
__global__ void __launch_bounds__(256) k_z1(const float* __restrict__ gT,
                                            const float* __restrict__ W,
                                            const float* __restrict__ b1,
                                            const float* __restrict__ b2,
                                            float* __restrict__ Z1) {
    int t = blockIdx.x >> 5, b = blockIdx.x & 31;
    __shared__ float sv[2048];
    __shared__ float zp[256];
    for (int v = threadIdx.x; v < 2048; v += 256) sv[v] = gT[t * NTOT + b * NNODE + v];
    __syncthreads();
    int row = threadIdx.x & 127, half = threadIdx.x >> 7;
    const float4* wp = (const float4*)(W + row * 2048 + half * 1024);
    const float4* sp = (const float4*)(sv + half * 1024);
    float acc = 0.f;
    for (int k = 0; k < 256; k++) {
        float4 w = wp[k], s = sp[k];
        acc += w.x * s.x + w.y * s.y + w.z * s.z + w.w * s.w;
    }
    zp[threadIdx.x] = acc;
    __syncthreads();
    if (threadIdx.x < 128)
        Z1[t * 4096 + b * 128 + threadIdx.x] =
            zp[threadIdx.x] + zp[threadIdx.x + 128] + b1[threadIdx.x] + b2[threadIdx.x];
}

// ---------- LSTM1 recurrence ----------
__global__ void __launch_bounds__(128) k_rec1(const float* __restrict__ Z1,
                                              const float* __restrict__ W,
                                              float* __restrict__ h1a) {
    int b = blockIdx.x, row = threadIdx.x;
    __shared__ float wh[128 * 33];
    __shared__ float hb[32];
    __shared__ float zb[128];
    for (int i = row; i < 4096; i += 128) {
        int r = i >> 5, j = i & 31;
        wh[r * 33 + j] = W[i];
    }
    if (row < 32) hb[row] = 0.f;
    float c = 0.f;
    __syncthreads();
    for (int t = 0; t < 12; t++) {
        float z = Z1[t * 4096 + b * 128 + row];
#pragma unroll
        for (int j = 0; j < 32; j++) z += hb[j] * wh[row * 33 + j];
        zb[row] = z;
        __syncthreads();
        if (row < 32) {
            float iv = zb[row], fv = zb[32 + row], gv = zb[64 + row], ov = zb[96 + row];
            c = sigmf(fv) * c + sigmf(iv) * tanhf(gv);
            float h = sigmf(ov) * tanhf(c);
            hb[row] = h;
            h1a[t * 1024 + b * 32 + row] = h;
        }
        __syncthreads();
    }
}

// ---------- Z2 input projection ----------
__global__ void k_z2(const float* __restrict__ h1a, const float* __restrict__ W,
                     const float* __restrict__ b1, const float* __restrict__ b2,
                     float* __restrict__ Z2) {
    int idx = blockIdx.x * 256 + threadIdx.x;   // 12*32*512
    int t = idx >> 14;
    int r = idx & 16383;
    int b = r >> 9, row = r & 511;
    const float* hp = h1a + t * 1024 + b * 32;
    const float4* wp = (const float4*)(W + row * 32);
    float acc = b1[row] + b2[row];
#pragma unroll
    for (int k = 0; k < 8; k++) {
        float4 w = wp[k];
        const float* h4 = hp + k * 4;
        acc += w.x * h4[0] + w.y * h4[1] + w.z * h4[2] + w.w * h4[3];
    }
    Z2[idx] = acc;
}

// ---------- LSTM2 recurrence ----------
__global__ void __launch_bounds__(512) k_rec2(const float* __restrict__ Z2,
                                              const float* __restrict__ W,
                                              float* __restrict__ h2l) {
    int b = blockIdx.x, row = threadIdx.x;
    __shared__ float hb[128];
    __shared__ float zb[512];
    if (row < 128) hb[row] = 0.f;
    float c = 0.f;
    __syncthreads();
    const float4* wp = (const float4*)(W + row * 128);
    for (int t = 0; t < 12; t++) {
        float z = Z2[t * 16384 + b * 512 + row];
#pragma unroll
        for (int k = 0; k < 32; k++) {
            float4 w = wp[k];
            const float* h4 = hb + k * 4;
            z += w.x * h4[0] + w.y * h4[1] + w.z * h4[2] + w.w * h4[3];
        }
        zb[row] = z;
        __syncthreads();
        if (row < 128) {
            float iv = zb[row], fv = zb[128 + row], gv = zb[256 + row], ov = zb[384 + row];
            c = sigmf(fv) * c + sigmf(iv) * tanhf(gv);
            float h = sigmf(ov) * tanhf(c);
            hb[row] = h;
            if (t == 11) h2l[b * 128 + row] = h;
        }
        __syncthreads();
    }
}

// ---------- final linear ----------
__global__ void __launch_bounds__(256) k_lin(const float* __restrict__ h2l,
                                             const float* __restrict__ W,
                                             const float* __restrict__ bl,
                                             const int* __restrict__ flags,
                                             void* __restrict__ outv) {
    __shared__ float hl[8 * 128];
    int bg = blockIdx.y;   // 0..3
    for (int i = threadIdx.x; i < 1024; i += 256) hl[i] = h2l[bg * 1024 + i];
    __syncthreads();
    int o = blockIdx.x * 256 + threadIdx.x;
    const float4* wp = (const float4*)(W + o * 128);
    float bb = bl[o];
    float acc[8];
#pragma unroll
    for (int b = 0; b < 8; b++) acc[b] = bb;
    for (int k = 0; k < 32; k++) {
        float4 w = wp[k];
#pragma unroll
        for (int b = 0; b < 8; b++) {
            const float* h4 = hl + b * 128 + k * 4;
            acc[b] += w.x * h4[0] + w.y * h4[1] + w.z * h4[2] + w.w * h4[3];
        }
    }
    int bf = flags[0];
    if (bf) {
        uint16_t* out = (uint16_t*)outv;
#pragma unroll
        for (int b = 0; b < 8; b++) out[(bg * 8 + b) * 18432 + o] = f2bf(acc[b]);
    } else {
        float* out = (float*)outv;
#pragma unroll
        for (int b = 0; b < 8; b++) out[(bg * 8 + b) * 18432 + o] = acc[b];
    }
}

extern "C" void kernel_launch(void* const* d_in, const int* in_sizes, int n_in,
                              void* d_out, int out_size, void* d_ws, size_t ws_size,
                              hipStream_t stream) {
    int E = in_sizes[1] / 2;

    float* ws = (float*)d_ws;
    int* flags = (int*)ws;                       // [16]
    float* cx    = ws + O_X;
    float* cWg   = ws + O_WG;
    float* cAs   = ws + O_AS;
    float* cAd   = ws + O_AD;
    float* cBias = ws + O_BIAS;
    float* cWih1 = ws + O_WIH1;
    float* cWhh1 = ws + O_WHH1;
    float* cBih1 = ws + O_BIH1;
    float* cBhh1 = ws + O_BHH1;
    float* cWih2 = ws + O_WIH2;
    float* cWhh2 = ws + O_WHH2;
    float* cBih2 = ws + O_BIH2;
    float* cBhh2 = ws + O_BHH2;
    float* cWlin = ws + O_WLIN;
    float* cBlin = ws + O_BLIN;

    float* hf  = ws + O_CONV_END;              // 6291456
    float* a_s = hf + 6291456;                 // 524288
    float* a_d = a_s + 524288;                 // 524288
    int* deg   = (int*)(a_d + 524288);         // 65536
    int* cnt2  = deg + 65536;                  // 65536
    int* offs  = cnt2 + 65536;                 // 65536
    int* bsum  = offs + 65536;                 // 256
    int* boff  = bsum + 256;                   // 256
    int* ssrc  = boff + 256;                   // 1048576
    float* gT  = (float*)(ssrc + 1048576);     // 786432
    float* Z1  = gT + 786432;                  // 49152
    float* h1a = Z1 + 49152;                   // 12288
    float* Z2  = h1a + 12288;                  // 196608
    float* h2l = Z2 + 196608;                  // 4096
    size_t needed = (size_t)((h2l + 4096) - ws) * 4;
    if (ws_size < needed) return;   // deterministic; leaves output zero as a diagnostic

    k_detect<<<1, 64, 0, stream>>>((const uint16_t*)d_in[0], (const int*)d_in[1], E, flags);
    k_conv<<<13731, 256, 0, stream>>>(d_in[0], d_in[2], d_in[3], d_in[4], d_in[5],
                                      d_in[6], d_in[7], d_in[8], d_in[9],
                                      d_in[10], d_in[11], d_in[12], d_in[13],
                                      d_in[14], d_in[15], ws, flags);
    k_zero<<<512, 256, 0, stream>>>(deg);      // deg + cnt2 (contiguous 131072 ints)

    k_node_feats<<<NTOT * 96 / 256, 256, 0, stream>>>(cx, cWg, hf);
    k_att<<<NTOT * 8 / 256, 256, 0, stream>>>(hf, cAs, cAd, a_s, a_d);
    k_hist<<<(E + 255) / 256, 256, 0, stream>>>((const int*)d_in[1], E, flags, deg);
    k_scan1<<<256, 256, 0, stream>>>(deg, bsum);
    k_scan2<<<1, 256, 0, stream>>>(bsum, boff);
    k_scan3<<<256, 256, 0, stream>>>(deg, boff, offs);
    k_scatter<<<(E + 255) / 256, 256, 0, stream>>>((const int*)d_in[1], E, flags, offs, cnt2, ssrc);
    k_agg<<<NTOT / 4, 256, 0, stream>>>(hf, a_s, a_d, offs, deg, ssrc, cBias, gT);
    k_z1<<<384, 256, 0, stream>>>(gT, cWih1, cBih1, cBhh1, Z1);
    k_rec1<<<32, 128, 0, stream>>>(Z1, cWhh1, h1a);
    k_z2<<<768, 256, 0, stream>>>(h1a, cWih2, cBih2, cBhh2, Z2);
    k_rec2<<<32, 512, 0, stream>>>(Z2, cWhh2, h2l);
    k_lin<<<dim3(72, 4), 256, 0, stream>>>(h2l, cWlin, cBlin, flags, d_out);
}

// Round 3
// 456.933 us; speedup vs baseline: 1.1692x; 1.1692x over previous
//
#include <hip/hip_runtime.h>
#include <hip/hip_bf16.h>
#include <stdint.h>

#define NTOT 65536   // B * N_NODE
#define NNODE 2048
#define CIN 12

__device__ __forceinline__ float bf2f(uint32_t u) {
    union { uint32_t i; float f; } v; v.i = u << 16; return v.f;
}
__device__ __forceinline__ uint16_t f2bf(float f) {
    union { float f; uint32_t i; } v; v.f = f;
    uint32_t x = v.i;
    uint32_t r = x + 0x7fffu + ((x >> 16) & 1u);
    return (uint16_t)(r >> 16);
}
__device__ __forceinline__ float bflo(uint32_t u) { return bf2f(u & 0xffffu); }
__device__ __forceinline__ float bfhi(uint32_t u) { return bf2f(u >> 16); }
__device__ __forceinline__ float sigmf(float x) { return 1.0f / (1.0f + __expf(-x)); }
__device__ __forceinline__ float lrelu(float v) { return v > 0.f ? v : 0.2f * v; }

// ---------------- dtype / layout detection ----------------
__global__ void k_detect(const uint16_t* __restrict__ x16, const int* __restrict__ e32,
                         int E, int* __restrict__ flags) {
    if (threadIdx.x == 0 && blockIdx.x == 0) {
        int sane = 0;
        for (int i = 0; i < 128; i++) {
            uint32_t u = x16[2 * i];
            uint32_t ex = (u >> 7) & 0xFF;
            if (ex >= 0x60 && ex <= 0x9F) sane++;
        }
        flags[0] = (sane >= 100) ? 1 : 0;
        int nz = 0;
        for (int i = 0; i < 64; i++)
            if (e32[2 * i + 1] != 0) nz++;
        flags[1] = (nz == 0) ? 2 : 1;
    }
}

// ---------------- input normalization to fp32 ----------------
__device__ __forceinline__ void cvt(const void* s, float* d, int i, int bf) {
    d[i] = bf ? bf2f(((const uint16_t*)s)[i]) : ((const float*)s)[i];
}

#define O_X    16
#define O_WG   786448
#define O_AS   787600
#define O_AD   787696
#define O_BIAS 787792
#define O_WIH1 787808
#define O_WHH1 1049952
#define O_BIH1 1054048
#define O_BHH1 1054176
#define O_WIH2 1054304
#define O_WHH2 1070688
#define O_BIH2 1136224
#define O_BHH2 1136736
#define O_WLIN 1137248
#define O_BLIN 3496544
#define O_CONV_END 3514976

__global__ void __launch_bounds__(256) k_conv(
    const void* x, const void* wg, const void* as_, const void* ad_, const void* bs,
    const void* w1, const void* wh1, const void* b1, const void* bb1,
    const void* w2, const void* wh2, const void* b2, const void* bb2,
    const void* wl, const void* bl, float* __restrict__ ws, const int* __restrict__ flags) {
    int bf = flags[0];
    int i = blockIdx.x * 256 + threadIdx.x;
    if (i < 786432)  { cvt(x,   ws + O_X,    i, bf); return; } i -= 786432;
    if (i < 1152)    { cvt(wg,  ws + O_WG,   i, bf); return; } i -= 1152;
    if (i < 96)      { cvt(as_, ws + O_AS,   i, bf); return; } i -= 96;
    if (i < 96)      { cvt(ad_, ws + O_AD,   i, bf); return; } i -= 96;
    if (i < 12)      { cvt(bs,  ws + O_BIAS, i, bf); return; } i -= 12;
    if (i < 262144)  { cvt(w1,  ws + O_WIH1, i, bf); return; } i -= 262144;
    if (i < 4096)    { cvt(wh1, ws + O_WHH1, i, bf); return; } i -= 4096;
    if (i < 128)     { cvt(b1,  ws + O_BIH1, i, bf); return; } i -= 128;
    if (i < 128)     { cvt(bb1, ws + O_BHH1, i, bf); return; } i -= 128;
    if (i < 16384)   { cvt(w2,  ws + O_WIH2, i, bf); return; } i -= 16384;
    if (i < 65536)   { cvt(wh2, ws + O_WHH2, i, bf); return; } i -= 65536;
    if (i < 512)     { cvt(b2,  ws + O_BIH2, i, bf); return; } i -= 512;
    if (i < 512)     { cvt(bb2, ws + O_BHH2, i, bf); return; } i -= 512;
    if (i < 2359296) { cvt(wl,  ws + O_WLIN, i, bf); return; } i -= 2359296;
    if (i < 18432)   { cvt(bl,  ws + O_BLIN, i, bf); }
}

__global__ void k_zero(int* __restrict__ p) {
    p[blockIdx.x * 256 + threadIdx.x] = 0;
}

// ---------- GAT node transform: hfb[n][96] = bf16(x[n][:] @ W_gat) ----------
__global__ void k_node_feats(const float* __restrict__ x, const float* __restrict__ Wg,
                             uint16_t* __restrict__ hfb) {
    int idx = blockIdx.x * 256 + threadIdx.x;   // NTOT*96
    int n = idx / 96, o = idx % 96;
    const float* xr = x + n * CIN;
    float acc = 0.f;
#pragma unroll
    for (int k = 0; k < CIN; k++) acc += xr[k] * Wg[k * 96 + o];
    hfb[idx] = f2bf(acc);
}

// ---------- attention scores (from bf16 hfb) ----------
__global__ void k_att(const uint16_t* __restrict__ hfb, const float* __restrict__ att_s,
                      const float* __restrict__ att_d, float* __restrict__ a_s,
                      float* __restrict__ a_d) {
    int idx = blockIdx.x * 256 + threadIdx.x;   // NTOT*8
    int n = idx >> 3, h = idx & 7;
    const uint32_t* hr = (const uint32_t*)(hfb + n * 96 + h * 12);  // 12 ushorts = 6 uints
    float s = 0.f, d = 0.f;
#pragma unroll
    for (int p = 0; p < 6; p++) {
        uint32_t u = hr[p];
        float v0 = bflo(u), v1 = bfhi(u);
        s += v0 * att_s[h * 12 + 2 * p] + v1 * att_s[h * 12 + 2 * p + 1];
        d += v0 * att_d[h * 12 + 2 * p] + v1 * att_d[h * 12 + 2 * p + 1];
    }
    a_s[idx] = s; a_d[idx] = d;
}

// ---------- CSR build ----------
__global__ void k_hist(const int* __restrict__ e, int E, const int* __restrict__ flags,
                       int* __restrict__ deg) {
    int i = blockIdx.x * 256 + threadIdx.x;
    if (i < E) {
        long st = flags[1];
        atomicAdd(&deg[e[st * (E + i)]], 1);
    }
}

__global__ void k_scan1(const int* __restrict__ deg, int* __restrict__ bsum) {
    __shared__ int s[256];
    s[threadIdx.x] = deg[blockIdx.x * 256 + threadIdx.x];
    __syncthreads();
    for (int off = 128; off > 0; off >>= 1) {
        if (threadIdx.x < off) s[threadIdx.x] += s[threadIdx.x + off];
        __syncthreads();
    }
    if (threadIdx.x == 0) bsum[blockIdx.x] = s[0];
}

__global__ void k_scan2(const int* __restrict__ bsum, int* __restrict__ boff) {
    __shared__ int s[256];
    int t = threadIdx.x;
    int v = bsum[t];
    s[t] = v; __syncthreads();
    for (int off = 1; off < 256; off <<= 1) {
        int a = (t >= off) ? s[t - off] : 0;
        __syncthreads();
        s[t] += a;
        __syncthreads();
    }
    boff[t] = s[t] - v;
}

__global__ void k_scan3(const int* __restrict__ deg, const int* __restrict__ boff,
                        int* __restrict__ offs) {
    __shared__ int s[256];
    int t = threadIdx.x;
    int i = blockIdx.x * 256 + t;
    int v = deg[i];
    s[t] = v; __syncthreads();
    for (int off = 1; off < 256; off <<= 1) {
        int a = (t >= off) ? s[t - off] : 0;
        __syncthreads();
        s[t] += a;
        __syncthreads();
    }
    offs[i] = boff[blockIdx.x] + s[t] - v;
}

__global__ void k_scatter(const int* __restrict__ e, int E, const int* __restrict__ flags,
                          const int* __restrict__ offs, int* __restrict__ cur,
                          int* __restrict__ ssrc) {
    int i = blockIdx.x * 256 + threadIdx.x;
    if (i < E) {
        long st = flags[1];
        int s = e[st * i];
        int d = e[st * (E + i)];
        int pos = offs[d] + atomicAdd(&cur[d], 1);
        ssrc[pos] = s;
    }
}

// ---------- GAT aggregation v2: no max pass, LDS-staged edge weights ----------
__global__ void __launch_bounds__(256) k_agg(
    const uint16_t* __restrict__ hfb, const float* __restrict__ a_s, const float* __restrict__ a_d,
    const int* __restrict__ offs, const int* __restrict__ deg, const int* __restrict__ ssrc,
    const float* __restrict__ bias, float* __restrict__ gT) {
    __shared__ float wbuf[4][512];
    __shared__ int sbuf[4][64];
    __shared__ float lacc[4][96];
    __shared__ int ds[4];
    int tid = threadIdx.x, wave = tid >> 6, lane = tid & 63;
    int node = blockIdx.x * 4 + wave;
    int beg = offs[node], d = deg[node];
    if (lane == 0) ds[wave] = d;

    const float4* d4 = (const float4*)(a_d + node * 8);
    float4 dd0 = d4[0], dd1 = d4[1];
    float adr[8] = {dd0.x, dd0.y, dd0.z, dd0.w, dd1.x, dd1.y, dd1.z, dd1.w};
    const float4* s4 = (const float4*)(a_s + node * 8);
    float4 ss0 = s4[0], ss1 = s4[1];
    float asr[8] = {ss0.x, ss0.y, ss0.z, ss0.w, ss1.x, ss1.y, ss1.z, ss1.w};
    __syncthreads();
    int dm = max(max(ds[0], ds[1]), max(ds[2], ds[3]));
    int nch = (dm + 63) >> 6;

    int ch0 = lane, head0 = lane / 12;
    int ch1 = lane + 64, head1 = (lane + 64) / 12;
    bool has1 = lane < 32;

    // self-loop contribution
    float w0s = __expf(lrelu(asr[head0] + adr[head0]));
    float acc0 = w0s * bf2f(hfb[node * 96 + ch0]);
    float wsum0 = w0s;
    float acc1 = 0.f, wsum1 = 0.f;
    if (has1) {
        float w1s = __expf(lrelu(asr[head1] + adr[head1]));
        acc1 = w1s * bf2f(hfb[node * 96 + ch1]);
        wsum1 = w1s;
    }

    for (int c = 0; c < nch; c++) {
        int kbase = c * 64;
        int rem = d - kbase;
        if (rem > 64) rem = 64;
        if (lane < rem) {
            int s = ssrc[beg + kbase + lane];
            sbuf[wave][lane] = s;
            const float4* q4 = (const float4*)(a_s + s * 8);
            float4 q0 = q4[0], q1 = q4[1];
            float w0 = __expf(lrelu(q0.x + adr[0]));
            float w1 = __expf(lrelu(q0.y + adr[1]));
            float w2 = __expf(lrelu(q0.z + adr[2]));
            float w3 = __expf(lrelu(q0.w + adr[3]));
            float w4 = __expf(lrelu(q1.x + adr[4]));
            float w5 = __expf(lrelu(q1.y + adr[5]));
            float w6 = __expf(lrelu(q1.z + adr[6]));
            float w7 = __expf(lrelu(q1.w + adr[7]));
            float4* wp = (float4*)&wbuf[wave][lane * 8];
            wp[0] = make_float4(w0, w1, w2, w3);
            wp[1] = make_float4(w4, w5, w6, w7);
        }
        __syncthreads();
        for (int k = 0; k < rem; k++) {
            int s = sbuf[wave][k];
            float w0 = wbuf[wave][k * 8 + head0];
            acc0 += w0 * bf2f(hfb[s * 96 + ch0]);
            wsum0 += w0;
            if (has1) {
                float w1v = wbuf[wave][k * 8 + head1];
                acc1 += w1v * bf2f(hfb[s * 96 + ch1]);
                wsum1 += w1v;
            }
        }
        __syncthreads();
    }

    lacc[wave][ch0] = acc0 / wsum0;
    if (has1) lacc[wave][ch1] = acc1 / wsum1;
    __syncthreads();

    if (lane < 12) {
        float s = 0.f;
#pragma unroll
        for (int h = 0; h < 8; h++) s += lacc[wave][h * 12 + lane];
        gT[lane * NTOT + node] = s * 0.125f + bias[lane];
    }
}

// ---------- Z1: dual-path (raw bf16 W or converted fp32 W) ----------
__global__ void __launch_bounds__(256) k_z1(const float* __restrict__ gT,
                                            const void* __restrict__ Wraw,
                                            const float* __restrict__ Wf,
                                            const float* __restrict__ b1,
                                            const float* __restrict__ b2,
                                            const int* __restrict__ flags,
                                            float* __restrict__ Z1) {
    int t = blockIdx.x >> 5, b = blockIdx.x & 31;
    __shared__ float sv[2048];
    __shared__ float zp[256];
    for (int v = threadIdx.x; v < 2048; v += 256) sv[v] = gT[t * NTOT + b * NNODE + v];
    __syncthreads();
    int row = threadIdx.x & 127, half = threadIdx.x >> 7;
    const float4* sp = (const float4*)(sv + half * 1024);
    float acc = 0.f;
    if (flags[0]) {
        const uint4* wp = (const uint4*)((const uint16_t*)Wraw + row * 2048 + half * 1024);
        for (int k = 0; k < 128; k++) {
            uint4 u = wp[k];
            float4 A = sp[2 * k], B = sp[2 * k + 1];
            acc += bflo(u.x) * A.x + bfhi(u.x) * A.y + bflo(u.y) * A.z + bfhi(u.y) * A.w
                 + bflo(u.z) * B.x + bfhi(u.z) * B.y + bflo(u.w) * B.z + bfhi(u.w) * B.w;
        }
    } else {
        const float4* wp = (const float4*)(Wf + row * 2048 + half * 1024);
        for (int k = 0; k < 256; k++) {
            float4 w = wp[k], s = sp[k];
            acc += w.x * s.x + w.y * s.y + w.z * s.z + w.w * s.w;
        }
    }
    zp[threadIdx.x] = acc;
    __syncthreads();
    if (threadIdx.x < 128)
        Z1[t * 4096 + b * 128 + threadIdx.x] =
            zp[threadIdx.x] + zp[threadIdx.x + 128] + b1[threadIdx.x] + b2[threadIdx.x];
}

// ---------- LSTM1 recurrence ----------
__global__ void __launch_bounds__(128) k_rec1(const float* __restrict__ Z1,
                                              const float* __restrict__ W,
                                              float* __restrict__ h1a) {
    int b = blockIdx.x, row = threadIdx.x;
    __shared__ float wh[128 * 33];
    __shared__ float hb[32];
    __shared__ float zb[128];
    for (int i = row; i < 4096; i += 128) {
        int r = i >> 5, j = i & 31;
        wh[r * 33 + j] = W[i];
    }
    if (row < 32) hb[row] = 0.f;
    float c = 0.f;
    __syncthreads();
    for (int t = 0; t < 12; t++) {
        float z = Z1[t * 4096 + b * 128 + row];
#pragma unroll
        for (int j = 0; j < 32; j++) z += hb[j] * wh[row * 33 + j];
        zb[row] = z;
        __syncthreads();
        if (row < 32) {
            float iv = zb[row], fv = zb[32 + row], gv = zb[64 + row], ov = zb[96 + row];
            c = sigmf(fv) * c + sigmf(iv) * tanhf(gv);
            float h = sigmf(ov) * tanhf(c);
            hb[row] = h;
            h1a[t * 1024 + b * 32 + row] = h;
        }
        __syncthreads();
    }
}

// ---------- Z2 input projection ----------
__global__ void k_z2(const float* __restrict__ h1a, const float* __restrict__ W,
                     const float* __restrict__ b1, const float* __restrict__ b2,
                     float* __restrict__ Z2) {
    int idx = blockIdx.x * 256 + threadIdx.x;   // 12*32*512
    int t = idx >> 14;
    int r = idx & 16383;
    int b = r >> 9, row = r & 511;
    const float* hp = h1a + t * 1024 + b * 32;
    const float4* wp = (const float4*)(W + row * 32);
    float acc = b1[row] + b2[row];
#pragma unroll
    for (int k = 0; k < 8; k++) {
        float4 w = wp[k];
        const float* h4 = hp + k * 4;
        acc += w.x * h4[0] + w.y * h4[1] + w.z * h4[2] + w.w * h4[3];
    }
    Z2[idx] = acc;
}

// ---------- LSTM2 recurrence ----------
__global__ void __launch_bounds__(512) k_rec2(const float* __restrict__ Z2,
                                              const float* __restrict__ W,
                                              float* __restrict__ h2l) {
    int b = blockIdx.x, row = threadIdx.x;
    __shared__ float hb[128];
    __shared__ float zb[512];
    if (row < 128) hb[row] = 0.f;
    float c = 0.f;
    __syncthreads();
    const float4* wp = (const float4*)(W + row * 128);
    for (int t = 0; t < 12; t++) {
        float z = Z2[t * 16384 + b * 512 + row];
#pragma unroll
        for (int k = 0; k < 32; k++) {
            float4 w = wp[k];
            const float* h4 = hb + k * 4;
            z += w.x * h4[0] + w.y * h4[1] + w.z * h4[2] + w.w * h4[3];
        }
        zb[row] = z;
        __syncthreads();
        if (row < 128) {
            float iv = zb[row], fv = zb[128 + row], gv = zb[256 + row], ov = zb[384 + row];
            c = sigmf(fv) * c + sigmf(iv) * tanhf(gv);
            float h = sigmf(ov) * tanhf(c);
            hb[row] = h;
            if (t == 11) h2l[b * 128 + row] = h;
        }
        __syncthreads();
    }
}

// ---------- final linear: dual-path W ----------
__global__ void __launch_bounds__(256) k_lin(const float* __restrict__ h2l,
                                             const void* __restrict__ Wraw,
                                             const float* __restrict__ Wf,
                                             const float* __restrict__ bl,
                                             const int* __restrict__ flags,
                                             void* __restrict__ outv) {
    __shared__ float hl[8 * 128];
    int bg = blockIdx.y;   // 0..3
    for (int i = threadIdx.x; i < 1024; i += 256) hl[i] = h2l[bg * 1024 + i];
    __syncthreads();
    int o = blockIdx.x * 256 + threadIdx.x;
    float bb = bl[o];
    float acc[8];
#pragma unroll
    for (int b = 0; b < 8; b++) acc[b] = bb;
    int bf = flags[0];
    if (bf) {
        const uint4* wp = (const uint4*)((const uint16_t*)Wraw + o * 128);
        for (int k = 0; k < 16; k++) {
            uint4 u = wp[k];
            float w0 = bflo(u.x), w1 = bfhi(u.x), w2 = bflo(u.y), w3 = bfhi(u.y);
            float w4 = bflo(u.z), w5 = bfhi(u.z), w6 = bflo(u.w), w7 = bfhi(u.w);
#pragma unroll
            for (int b = 0; b < 8; b++) {
                const float* h8 = hl + b * 128 + k * 8;
                acc[b] += w0 * h8[0] + w1 * h8[1] + w2 * h8[2] + w3 * h8[3]
                        + w4 * h8[4] + w5 * h8[5] + w6 * h8[6] + w7 * h8[7];
            }
        }
    } else {
        const float4* wp = (const float4*)(Wf + o * 128);
        for (int k = 0; k < 32; k++) {
            float4 w = wp[k];
#pragma unroll
            for (int b = 0; b < 8; b++) {
                const float* h4 = hl + b * 128 + k * 4;
                acc[b] += w.x * h4[0] + w.y * h4[1] + w.z * h4[2] + w.w * h4[3];
            }
        }
    }
    if (bf) {
        uint16_t* out = (uint16_t*)outv;
#pragma unroll
        for (int b = 0; b < 8; b++) out[(bg * 8 + b) * 18432 + o] = f2bf(acc[b]);
    } else {
        float* out = (float*)outv;
#pragma unroll
        for (int b = 0; b < 8; b++) out[(bg * 8 + b) * 18432 + o] = acc[b];
    }
}

extern "C" void kernel_launch(void* const* d_in, const int* in_sizes, int n_in,
                              void* d_out, int out_size, void* d_ws, size_t ws_size,
                              hipStream_t stream) {
    int E = in_sizes[1] / 2;

    float* ws = (float*)d_ws;
    int* flags = (int*)ws;
    float* cx    = ws + O_X;
    float* cWg   = ws + O_WG;
    float* cAs   = ws + O_AS;
    float* cAd   = ws + O_AD;
    float* cBias = ws + O_BIAS;
    float* cWih1 = ws + O_WIH1;
    float* cWhh1 = ws + O_WHH1;
    float* cBih1 = ws + O_BIH1;
    float* cBhh1 = ws + O_BHH1;
    float* cWih2 = ws + O_WIH2;
    float* cWhh2 = ws + O_WHH2;
    float* cBih2 = ws + O_BIH2;
    float* cBhh2 = ws + O_BHH2;
    float* cWlin = ws + O_WLIN;
    float* cBlin = ws + O_BLIN;

    float* base = ws + O_CONV_END;
    uint16_t* hfb = (uint16_t*)base;           // NTOT*96 ushorts = 3145728 floats
    float* a_s = base + 3145728;               // 524288
    float* a_d = a_s + 524288;                 // 524288
    int* deg   = (int*)(a_d + 524288);         // 65536
    int* cnt2  = deg + 65536;                  // 65536
    int* offs  = cnt2 + 65536;                 // 65536
    int* bsum  = offs + 65536;                 // 256
    int* boff  = bsum + 256;                   // 256
    int* ssrc  = boff + 256;                   // 1048576
    float* gT  = (float*)(ssrc + 1048576);     // 786432
    float* Z1  = gT + 786432;                  // 49152
    float* h1a = Z1 + 49152;                   // 12288
    float* Z2  = h1a + 12288;                  // 196608
    float* h2l = Z2 + 196608;                  // 4096
    size_t needed = (size_t)((h2l + 4096) - ws) * 4;
    if (ws_size < needed) return;

    k_detect<<<1, 64, 0, stream>>>((const uint16_t*)d_in[0], (const int*)d_in[1], E, flags);
    k_conv<<<13731, 256, 0, stream>>>(d_in[0], d_in[2], d_in[3], d_in[4], d_in[5],
                                      d_in[6], d_in[7], d_in[8], d_in[9],
                                      d_in[10], d_in[11], d_in[12], d_in[13],
                                      d_in[14], d_in[15], ws, flags);
    k_zero<<<512, 256, 0, stream>>>(deg);

    k_node_feats<<<NTOT * 96 / 256, 256, 0, stream>>>(cx, cWg, hfb);
    k_att<<<NTOT * 8 / 256, 256, 0, stream>>>(hfb, cAs, cAd, a_s, a_d);
    k_hist<<<(E + 255) / 256, 256, 0, stream>>>((const int*)d_in[1], E, flags, deg);
    k_scan1<<<256, 256, 0, stream>>>(deg, bsum);
    k_scan2<<<1, 256, 0, stream>>>(bsum, boff);
    k_scan3<<<256, 256, 0, stream>>>(deg, boff, offs);
    k_scatter<<<(E + 255) / 256, 256, 0, stream>>>((const int*)d_in[1], E, flags, offs, cnt2, ssrc);
    k_agg<<<NTOT / 4, 256, 0, stream>>>(hfb, a_s, a_d, offs, deg, ssrc, cBias, gT);
    k_z1<<<384, 256, 0, stream>>>(gT, d_in[6], cWih1, cBih1, cBhh1, flags, Z1);
    k_rec1<<<32, 128, 0, stream>>>(Z1, cWhh1, h1a);
    k_z2<<<768, 256, 0, stream>>>(h1a, cWih2, cBih2, cBhh2, Z2);
    k_rec2<<<32, 512, 0, stream>>>(Z2, cWhh2, h2l);
    k_lin<<<dim3(72, 4), 256, 0, stream>>>(h2l, d_in[14], cWlin, cBlin, flags, d_out);
}

// Round 4
// 414.971 us; speedup vs baseline: 1.2874x; 1.1011x over previous
//
#include <hip/hip_runtime.h>
#include <hip/hip_bf16.h>
#include <stdint.h>

#define NTOT 65536   // B * N_NODE
#define NNODE 2048
#define CIN 12

__device__ __forceinline__ float bf2f(uint32_t u) {
    union { uint32_t i; float f; } v; v.i = u << 16; return v.f;
}
__device__ __forceinline__ uint16_t f2bf(float f) {
    union { float f; uint32_t i; } v; v.f = f;
    uint32_t x = v.i;
    uint32_t r = x + 0x7fffu + ((x >> 16) & 1u);
    return (uint16_t)(r >> 16);
}
__device__ __forceinline__ float bflo(uint32_t u) { return bf2f(u & 0xffffu); }
__device__ __forceinline__ float bfhi(uint32_t u) { return bf2f(u >> 16); }
__device__ __forceinline__ float sigmf(float x) { return 1.0f / (1.0f + __expf(-x)); }
__device__ __forceinline__ float lrelu(float v) { return v > 0.f ? v : 0.2f * v; }

// ---------------- dtype / layout detection (one wave) ----------------
__global__ void k_detect(const uint16_t* __restrict__ x16, const int* __restrict__ e32,
                         int* __restrict__ flags) {
    int lane = threadIdx.x;
    uint32_t u = x16[2 * lane];
    uint32_t ex = (u >> 7) & 0xFF;
    bool sane = (ex >= 0x60 && ex <= 0x9F) || (u == 0);
    unsigned long long bs = __ballot(sane);
    bool hi_zero = (e32[2 * lane + 1] == 0);
    unsigned long long bz = __ballot(hi_zero);
    if (lane == 0) {
        flags[0] = (__popcll(bs) >= 52) ? 1 : 0;   // bf16 if most even halves look like small floats
        flags[1] = (__popcll(bz) == 64) ? 2 : 1;   // int64 stride 2 words, else int32
    }
}

// ---------------- small-tensor conversion to fp32 ----------------
__device__ __forceinline__ void cvt(const void* s, float* d, int i, int bf) {
    d[i] = bf ? bf2f(((const uint16_t*)s)[i]) : ((const float*)s)[i];
}

#define O_WG   16
#define O_AS   1168
#define O_AD   1264
#define O_BIAS 1360
#define O_BIH1 1376
#define O_BHH1 1504
#define O_BIH2 1632
#define O_BHH2 2144
#define O_BLIN 2656
#define O_END  21088

__global__ void __launch_bounds__(256) k_conv(
    const void* wg, const void* as_, const void* ad_, const void* bs,
    const void* b1, const void* bb1, const void* b2, const void* bb2,
    const void* bl, float* __restrict__ ws, const int* __restrict__ flags) {
    int bf = flags[0];
    int i = blockIdx.x * 256 + threadIdx.x;
    if (i < 1152)  { cvt(wg,  ws + O_WG,   i, bf); return; } i -= 1152;
    if (i < 96)    { cvt(as_, ws + O_AS,   i, bf); return; } i -= 96;
    if (i < 96)    { cvt(ad_, ws + O_AD,   i, bf); return; } i -= 96;
    if (i < 12)    { cvt(bs,  ws + O_BIAS, i, bf); return; } i -= 12;
    if (i < 128)   { cvt(b1,  ws + O_BIH1, i, bf); return; } i -= 128;
    if (i < 128)   { cvt(bb1, ws + O_BHH1, i, bf); return; } i -= 128;
    if (i < 512)   { cvt(b2,  ws + O_BIH2, i, bf); return; } i -= 512;
    if (i < 512)   { cvt(bb2, ws + O_BHH2, i, bf); return; } i -= 512;
    if (i < 18432) { cvt(bl,  ws + O_BLIN, i, bf); }
}

__global__ void k_zero(int* __restrict__ p) {
    p[blockIdx.x * 256 + threadIdx.x] = 0;
}

// ---------- fused node transform + attention scores ----------
// block = 32 nodes; phase1: hf = x@Wg (to LDS + bf16 global); phase2: a_s/a_d
__global__ void __launch_bounds__(256) k_nfa(const void* __restrict__ xraw,
                                             const float* __restrict__ Wg,
                                             const float* __restrict__ att,   // [as 96][ad 96]
                                             const int* __restrict__ flags,
                                             uint16_t* __restrict__ hfb,
                                             float* __restrict__ a_s, float* __restrict__ a_d) {
    __shared__ float sx[384];
    __shared__ float sw[1152];
    __shared__ float satt[192];
    __shared__ float sh[3072];
    int tid = threadIdx.x;
    int n0 = blockIdx.x * 32;
    if (flags[0]) {
        const uint32_t* xp = (const uint32_t*)xraw;
        for (int i = tid; i < 192; i += 256) {
            uint32_t u = xp[n0 * 6 + i];
            sx[2 * i] = bflo(u); sx[2 * i + 1] = bfhi(u);
        }
    } else {
        const float* xp = (const float*)xraw;
        for (int i = tid; i < 384; i += 256) sx[i] = xp[n0 * 12 + i];
    }
    for (int i = tid; i < 1152; i += 256) sw[i] = Wg[i];
    if (tid < 192) satt[tid] = att[tid];
    __syncthreads();
#pragma unroll
    for (int r = 0; r < 12; r++) {
        int idx = r * 256 + tid;
        int n = idx / 96, o = idx % 96;
        float acc = 0.f;
#pragma unroll
        for (int k = 0; k < 12; k++) acc += sx[n * 12 + k] * sw[k * 96 + o];
        sh[idx] = acc;
        hfb[n0 * 96 + idx] = f2bf(acc);
    }
    __syncthreads();
    {
        int nl = tid >> 3, h = tid & 7;
        const float* hr = sh + nl * 96 + h * 12;
        float s = 0.f, dd = 0.f;
#pragma unroll
        for (int c = 0; c < 12; c++) {
            float v = hr[c];
            s += v * satt[h * 12 + c];
            dd += v * satt[96 + h * 12 + c];
        }
        a_s[n0 * 8 + tid] = s;
        a_d[n0 * 8 + tid] = dd;
    }
}

// ---------- CSR build: hist stores within-bucket rank ----------
__global__ void k_hist(const int* __restrict__ e, int E, const int* __restrict__ flags,
                       int* __restrict__ deg, int* __restrict__ rank) {
    int i = blockIdx.x * 256 + threadIdx.x;
    if (i < E) {
        long st = flags[1];
        int d = e[st * (E + i)];
        rank[i] = atomicAdd(&deg[d], 1);
    }
}

// local exclusive scan + per-block sums
__global__ void k_scanA(const int* __restrict__ deg, int* __restrict__ offsL,
                        int* __restrict__ bsum) {
    __shared__ int s[256];
    int t = threadIdx.x, i = blockIdx.x * 256 + t;
    int v = deg[i];
    s[t] = v; __syncthreads();
    for (int off = 1; off < 256; off <<= 1) {
        int a = (t >= off) ? s[t - off] : 0;
        __syncthreads();
        s[t] += a;
        __syncthreads();
    }
    offsL[i] = s[t] - v;
    if (t == 255) bsum[blockIdx.x] = s[255];
}

// exclusive scan of the 256 block sums
__global__ void k_scanB(const int* __restrict__ bsum, int* __restrict__ boff) {
    __shared__ int s[256];
    int t = threadIdx.x;
    int v = bsum[t];
    s[t] = v; __syncthreads();
    for (int off = 1; off < 256; off <<= 1) {
        int a = (t >= off) ? s[t - off] : 0;
        __syncthreads();
        s[t] += a;
        __syncthreads();
    }
    boff[t] = s[t] - v;
}

__global__ void k_scatter(const int* __restrict__ e, int E, const int* __restrict__ flags,
                          const int* __restrict__ offsL, const int* __restrict__ boff,
                          const int* __restrict__ rank, int* __restrict__ ssrc) {
    int i = blockIdx.x * 256 + threadIdx.x;
    if (i < E) {
        long st = flags[1];
        int s = e[st * i];
        int d = e[st * (E + i)];
        ssrc[offsL[d] + boff[d >> 8] + rank[i]] = s;
    }
}

// ---------- GAT aggregation v3: lane = (edge-slot, head), 8 edges/iter ----------
__global__ void __launch_bounds__(256) k_agg(
    const uint16_t* __restrict__ hfb, const float* __restrict__ a_s, const float* __restrict__ a_d,
    const int* __restrict__ offsL, const int* __restrict__ boff, const int* __restrict__ deg,
    const int* __restrict__ ssrc, const float* __restrict__ bias, float* __restrict__ gT) {
    __shared__ float sres[4][12];
    int tid = threadIdx.x, wave = tid >> 6, lane = tid & 63;
    int node = blockIdx.x * 4 + wave;
    int beg = offsL[node] + boff[node >> 8];
    int d = deg[node];
    int sub = lane >> 3, h = lane & 7;
    float adh = a_d[node * 8 + h];
    float acc[12];
    float wsum = 0.f;
#pragma unroll
    for (int c = 0; c < 12; c++) acc[c] = 0.f;
    if (sub == 0) {   // self loop
        float w = __expf(lrelu(a_s[node * 8 + h] + adh));
        wsum = w;
        const uint2* hp = (const uint2*)(hfb + node * 96 + h * 12);
#pragma unroll
        for (int p = 0; p < 3; p++) {
            uint2 u = hp[p];
            acc[4 * p]     = w * bflo(u.x); acc[4 * p + 1] = w * bfhi(u.x);
            acc[4 * p + 2] = w * bflo(u.y); acc[4 * p + 3] = w * bfhi(u.y);
        }
    }
    for (int base = 0; base < d; base += 8) {
        int k = base + sub;
        if (k < d) {
            int s = ssrc[beg + k];
            float w = __expf(lrelu(a_s[s * 8 + h] + adh));
            wsum += w;
            const uint2* hp = (const uint2*)(hfb + s * 96 + h * 12);
#pragma unroll
            for (int p = 0; p < 3; p++) {
                uint2 u = hp[p];
                acc[4 * p]     += w * bflo(u.x); acc[4 * p + 1] += w * bfhi(u.x);
                acc[4 * p + 2] += w * bflo(u.y); acc[4 * p + 3] += w * bfhi(u.y);
            }
        }
    }
    // reduce across edge slots (xor 8,16,32)
#pragma unroll
    for (int off = 8; off <= 32; off <<= 1) {
        wsum += __shfl_xor(wsum, off, 64);
#pragma unroll
        for (int c = 0; c < 12; c++) acc[c] += __shfl_xor(acc[c], off, 64);
    }
    float inv = 1.f / wsum;
#pragma unroll
    for (int c = 0; c < 12; c++) acc[c] *= inv;
    // mean across heads (xor 1,2,4)
#pragma unroll
    for (int off = 1; off <= 4; off <<= 1) {
#pragma unroll
        for (int c = 0; c < 12; c++) acc[c] += __shfl_xor(acc[c], off, 64);
    }
    if (lane == 0) {
#pragma unroll
        for (int c = 0; c < 12; c++) sres[wave][c] = acc[c];
    }
    __syncthreads();
    if (tid < 48) {
        int no = tid / 12, c = tid % 12;
        gT[c * NTOT + blockIdx.x * 4 + no] = sres[no][c] * 0.125f + bias[c];
    }
}

// ---------- Z1 = seq @ Wih1^T + biases (dual-path W) ----------
__global__ void __launch_bounds__(256) k_z1(const float* __restrict__ gT,
                                            const void* __restrict__ Wraw,
                                            const float* __restrict__ b1,
                                            const float* __restrict__ b2,
                                            const int* __restrict__ flags,
                                            float* __restrict__ Z1) {
    int t = blockIdx.x >> 5, b = blockIdx.x & 31;
    __shared__ float sv[2048];
    __shared__ float zp[256];
    for (int v = threadIdx.x; v < 2048; v += 256) sv[v] = gT[t * NTOT + b * NNODE + v];
    __syncthreads();
    int row = threadIdx.x & 127, half = threadIdx.x >> 7;
    const float4* sp = (const float4*)(sv + half * 1024);
    float acc = 0.f;
    if (flags[0]) {
        const uint4* wp = (const uint4*)((const uint16_t*)Wraw + row * 2048 + half * 1024);
        for (int k = 0; k < 128; k++) {
            uint4 u = wp[k];
            float4 A = sp[2 * k], B = sp[2 * k + 1];
            acc += bflo(u.x) * A.x + bfhi(u.x) * A.y + bflo(u.y) * A.z + bfhi(u.y) * A.w
                 + bflo(u.z) * B.x + bfhi(u.z) * B.y + bflo(u.w) * B.z + bfhi(u.w) * B.w;
        }
    } else {
        const float4* wp = (const float4*)((const float*)Wraw + row * 2048 + half * 1024);
        for (int k = 0; k < 256; k++) {
            float4 w = wp[k], s = sp[k];
            acc += w.x * s.x + w.y * s.y + w.z * s.z + w.w * s.w;
        }
    }
    zp[threadIdx.x] = acc;
    __syncthreads();
    if (threadIdx.x < 128)
        Z1[t * 4096 + b * 128 + threadIdx.x] =
            zp[threadIdx.x] + zp[threadIdx.x + 128] + b1[threadIdx.x] + b2[threadIdx.x];
}

// ---------- LSTM1 recurrence (dual-path Whh1 staged to LDS) ----------
__global__ void __launch_bounds__(128) k_rec1(const float* __restrict__ Z1,
                                              const void* __restrict__ Wraw,
                                              const int* __restrict__ flags,
                                              float* __restrict__ h1a) {
    int b = blockIdx.x, row = threadIdx.x;
    __shared__ float wh[128 * 33];
    __shared__ float hb[32];
    __shared__ float zb[128];
    if (flags[0]) {
        const uint32_t* wp = (const uint32_t*)Wraw;
        for (int i = row; i < 2048; i += 128) {
            uint32_t u = wp[i];
            int e0 = 2 * i;
            wh[(e0 >> 5) * 33 + (e0 & 31)] = bflo(u);
            wh[(e0 >> 5) * 33 + (e0 & 31) + 1] = bfhi(u);
        }
    } else {
        const float* wp = (const float*)Wraw;
        for (int i = row; i < 4096; i += 128)
            wh[(i >> 5) * 33 + (i & 31)] = wp[i];
    }
    if (row < 32) hb[row] = 0.f;
    float c = 0.f;
    __syncthreads();
    for (int t = 0; t < 12; t++) {
        float z = Z1[t * 4096 + b * 128 + row];
#pragma unroll
        for (int j = 0; j < 32; j++) z += hb[j] * wh[row * 33 + j];
        zb[row] = z;
        __syncthreads();
        if (row < 32) {
            float iv = zb[row], fv = zb[32 + row], gv = zb[64 + row], ov = zb[96 + row];
            c = sigmf(fv) * c + sigmf(iv) * tanhf(gv);
            float h = sigmf(ov) * tanhf(c);
            hb[row] = h;
            h1a[t * 1024 + b * 32 + row] = h;
        }
        __syncthreads();
    }
}

// ---------- Z2 input projection (dual-path Wih2) ----------
__global__ void k_z2(const float* __restrict__ h1a, const void* __restrict__ Wraw,
                     const float* __restrict__ b1, const float* __restrict__ b2,
                     const int* __restrict__ flags, float* __restrict__ Z2) {
    int idx = blockIdx.x * 256 + threadIdx.x;   // 12*32*512
    int t = idx >> 14;
    int r = idx & 16383;
    int b = r >> 9, row = r & 511;
    const float* hp = h1a + t * 1024 + b * 32;
    float acc = b1[row] + b2[row];
    if (flags[0]) {
        const uint2* wp = (const uint2*)((const uint16_t*)Wraw + row * 32);
#pragma unroll
        for (int k = 0; k < 8; k++) {
            uint2 u = wp[k];
            const float* h4 = hp + k * 4;
            acc += bflo(u.x) * h4[0] + bfhi(u.x) * h4[1] + bflo(u.y) * h4[2] + bfhi(u.y) * h4[3];
        }
    } else {
        const float4* wp = (const float4*)((const float*)Wraw + row * 32);
#pragma unroll
        for (int k = 0; k < 8; k++) {
            float4 w = wp[k];
            const float* h4 = hp + k * 4;
            acc += w.x * h4[0] + w.y * h4[1] + w.z * h4[2] + w.w * h4[3];
        }
    }
    Z2[idx] = acc;
}

// ---------- LSTM2 recurrence: Whh2 row in registers (bf16 path) ----------
__global__ void __launch_bounds__(512) k_rec2(const float* __restrict__ Z2,
                                              const void* __restrict__ Wraw,
                                              const int* __restrict__ flags,
                                              float* __restrict__ h2l) {
    int b = blockIdx.x, row = threadIdx.x;
    __shared__ float hb[128];
    __shared__ float zb[512];
    if (row < 128) hb[row] = 0.f;
    float c = 0.f;
    int bf = flags[0];
    uint32_t wreg[64];
    if (bf) {
        const uint32_t* wp = (const uint32_t*)Wraw + row * 64;
#pragma unroll
        for (int j = 0; j < 64; j++) wreg[j] = wp[j];
    }
    __syncthreads();
    const float* wf = (const float*)Wraw + row * 128;
    for (int t = 0; t < 12; t++) {
        float z = Z2[t * 16384 + b * 512 + row];
        if (bf) {
#pragma unroll
            for (int j = 0; j < 64; j++) {
                uint32_t u = wreg[j];
                z += bflo(u) * hb[2 * j] + bfhi(u) * hb[2 * j + 1];
            }
        } else {
            for (int j = 0; j < 128; j += 4)
                z += wf[j] * hb[j] + wf[j + 1] * hb[j + 1]
                   + wf[j + 2] * hb[j + 2] + wf[j + 3] * hb[j + 3];
        }
        zb[row] = z;
        __syncthreads();
        if (row < 128) {
            float iv = zb[row], fv = zb[128 + row], gv = zb[256 + row], ov = zb[384 + row];
            c = sigmf(fv) * c + sigmf(iv) * tanhf(gv);
            float h = sigmf(ov) * tanhf(c);
            hb[row] = h;
            if (t == 11) h2l[b * 128 + row] = h;
        }
        __syncthreads();
    }
}

// ---------- final linear (dual-path W) ----------
__global__ void __launch_bounds__(256) k_lin(const float* __restrict__ h2l,
                                             const void* __restrict__ Wraw,
                                             const float* __restrict__ bl,
                                             const int* __restrict__ flags,
                                             void* __restrict__ outv) {
    __shared__ float hl[8 * 128];
    int bg = blockIdx.y;   // 0..3
    for (int i = threadIdx.x; i < 1024; i += 256) hl[i] = h2l[bg * 1024 + i];
    __syncthreads();
    int o = blockIdx.x * 256 + threadIdx.x;
    float bb = bl[o];
    float acc[8];
#pragma unroll
    for (int b = 0; b < 8; b++) acc[b] = bb;
    int bf = flags[0];
    if (bf) {
        const uint4* wp = (const uint4*)((const uint16_t*)Wraw + o * 128);
        for (int k = 0; k < 16; k++) {
            uint4 u = wp[k];
            float w0 = bflo(u.x), w1 = bfhi(u.x), w2 = bflo(u.y), w3 = bfhi(u.y);
            float w4 = bflo(u.z), w5 = bfhi(u.z), w6 = bflo(u.w), w7 = bfhi(u.w);
#pragma unroll
            for (int b = 0; b < 8; b++) {
                const float* h8 = hl + b * 128 + k * 8;
                acc[b] += w0 * h8[0] + w1 * h8[1] + w2 * h8[2] + w3 * h8[3]
                        + w4 * h8[4] + w5 * h8[5] + w6 * h8[6] + w7 * h8[7];
            }
        }
    } else {
        const float4* wp = (const float4*)((const float*)Wraw + o * 128);
        for (int k = 0; k < 32; k++) {
            float4 w = wp[k];
#pragma unroll
            for (int b = 0; b < 8; b++) {
                const float* h4 = hl + b * 128 + k * 4;
                acc[b] += w.x * h4[0] + w.y * h4[1] + w.z * h4[2] + w.w * h4[3];
            }
        }
    }
    if (bf) {
        uint16_t* out = (uint16_t*)outv;
#pragma unroll
        for (int b = 0; b < 8; b++) out[(bg * 8 + b) * 18432 + o] = f2bf(acc[b]);
    } else {
        float* out = (float*)outv;
#pragma unroll
        for (int b = 0; b < 8; b++) out[(bg * 8 + b) * 18432 + o] = acc[b];
    }
}

extern "C" void kernel_launch(void* const* d_in, const int* in_sizes, int n_in,
                              void* d_out, int out_size, void* d_ws, size_t ws_size,
                              hipStream_t stream) {
    int E = in_sizes[1] / 2;

    float* ws = (float*)d_ws;
    int* flags = (int*)ws;
    float* cWg   = ws + O_WG;
    float* cAtt  = ws + O_AS;    // a_s then a_d contiguous
    float* cBias = ws + O_BIAS;
    float* cBih1 = ws + O_BIH1;
    float* cBhh1 = ws + O_BHH1;
    float* cBih2 = ws + O_BIH2;
    float* cBhh2 = ws + O_BHH2;
    float* cBlin = ws + O_BLIN;

    float* base = ws + O_END;
    uint16_t* hfb = (uint16_t*)base;               // NTOT*96 bf16 = 3145728 floats
    float* a_s  = base + 3145728;                  // 524288
    float* a_d  = a_s + 524288;                    // 524288
    int* deg    = (int*)(a_d + 524288);            // 65536
    int* offsL  = deg + 65536;                     // 65536
    int* bsum   = offsL + 65536;                   // 256
    int* boff   = bsum + 256;                      // 256
    int* rank   = boff + 256;                      // E
    int* ssrc   = rank + E;                        // E
    float* gT   = (float*)(ssrc + E);              // 786432
    float* Z1   = gT + 786432;                     // 49152
    float* h1a  = Z1 + 49152;                      // 12288
    float* Z2   = h1a + 12288;                     // 196608
    float* h2l  = Z2 + 196608;                     // 4096
    size_t needed = (size_t)((h2l + 4096) - ws) * 4;
    if (ws_size < needed) return;

    k_detect<<<1, 64, 0, stream>>>((const uint16_t*)d_in[0], (const int*)d_in[1], flags);
    k_conv<<<83, 256, 0, stream>>>(d_in[2], d_in[3], d_in[4], d_in[5],
                                   d_in[8], d_in[9], d_in[12], d_in[13], d_in[15],
                                   ws, flags);
    k_zero<<<256, 256, 0, stream>>>(deg);

    k_nfa<<<2048, 256, 0, stream>>>(d_in[0], cWg, cAtt, flags, hfb, a_s, a_d);
    k_hist<<<(E + 255) / 256, 256, 0, stream>>>((const int*)d_in[1], E, flags, deg, rank);
    k_scanA<<<256, 256, 0, stream>>>(deg, offsL, bsum);
    k_scanB<<<1, 256, 0, stream>>>(bsum, boff);
    k_scatter<<<(E + 255) / 256, 256, 0, stream>>>((const int*)d_in[1], E, flags,
                                                   offsL, boff, rank, ssrc);
    k_agg<<<NTOT / 4, 256, 0, stream>>>(hfb, a_s, a_d, offsL, boff, deg, ssrc, cBias, gT);
    k_z1<<<384, 256, 0, stream>>>(gT, d_in[6], cBih1, cBhh1, flags, Z1);
    k_rec1<<<32, 128, 0, stream>>>(Z1, d_in[7], flags, h1a);
    k_z2<<<768, 256, 0, stream>>>(h1a, d_in[10], cBih2, cBhh2, flags, Z2);
    k_rec2<<<32, 512, 0, stream>>>(Z2, d_in[11], flags, h2l);
    k_lin<<<dim3(72, 4), 256, 0, stream>>>(h2l, d_in[14], cBlin, flags, d_out);
}